// Round 11
// baseline (948.049 us; speedup 1.0000x reference)
//
#include <hip/hip_runtime.h>

// Sparse 3D conv (Cin=1, Cout=16), stride-2 — 27-plane two-pass, the
// zero-divergence structure:
//   pass 1: every rulebook entry does ONE bf16 store g[k][o] (no branches,
//           no atomics, no barriers; (o,k) unique by construction)
//   pass 2: out[o,:] = sum_{k=0..26} g[k][o] * W[k,:]  (plain streaming
//           stores, overwrites every row -> no out memset)
//
// Why back to 27 planes: rounds 6-10 showed every sparse-path trick
// (global-counter compaction 72us, per-thread-channel atomics 319us,
// fused LDS drain 89us + occupancy 30%) costs more than the ~12us the
// 8-plane split saves in memset+read traffic. R4 proved this structure
// passes at absmax 0.0078; R5 proved the lean packed-register reduce;
// R8/9 proved 4-entry int4-vectorized ILP scatter.

typedef float vf4 __attribute__((ext_vector_type(4)));
typedef int   vi4 __attribute__((ext_vector_type(4)));

__device__ inline unsigned short f32_to_bf16_rne(float x) {
    unsigned int u = __float_as_uint(x);
    unsigned int r = 0x7FFFu + ((u >> 16) & 1u);
    return (unsigned short)((u + r) >> 16);
}

__global__ void __launch_bounds__(256)
scatter27(const float* __restrict__ feats,
          const int* __restrict__ in_idx,
          const int* __restrict__ out_idx,
          const int* __restrict__ k_idx,
          unsigned short* __restrict__ g,
          int M, int np) {
    int t = blockIdx.x * blockDim.x + threadIdx.x;
    int base = t * 4;
    if (base + 3 < M) {
        vi4 kk = *(const vi4*)&k_idx[base];    // 16B coalesced
        vi4 ii = *(const vi4*)&in_idx[base];
        vi4 oo = *(const vi4*)&out_idx[base];
        // 4 independent gathers in flight (MLP)
        float f0 = feats[ii.x], f1 = feats[ii.y],
              f2 = feats[ii.z], f3 = feats[ii.w];
        // one unconditional 2B store per entry; k IS the plane index
        g[(size_t)kk.x * np + oo.x] = f32_to_bf16_rne(f0);
        g[(size_t)kk.y * np + oo.y] = f32_to_bf16_rne(f1);
        g[(size_t)kk.z * np + oo.z] = f32_to_bf16_rne(f2);
        g[(size_t)kk.w * np + oo.w] = f32_to_bf16_rne(f3);
    } else if (base < M) {
        for (int m = base; m < M; ++m)
            g[(size_t)k_idx[m] * np + out_idx[m]] =
                f32_to_bf16_rne(feats[in_idx[m]]);
    }
}

__global__ void __launch_bounds__(256, 4)
reduce27(const unsigned int* __restrict__ g32,  // 27 planes as u32 (2x bf16)
         const float* __restrict__ weight,      // [27][16] f32
         float* __restrict__ out,
         int n_out, int half_np) {
    __shared__ float wlds[27 * 16];
    for (int i = threadIdx.x; i < 27 * 16; i += blockDim.x)
        wlds[i] = weight[i];
    __syncthreads();

    int t = blockIdx.x * blockDim.x + threadIdx.x;
    int o0 = t * 2;
    if (o0 >= n_out) return;

    // 27 independent coalesced streams, kept packed (27 VGPRs)
    unsigned int gu[27];
    #pragma unroll
    for (int k = 0; k < 27; ++k)
        gu[k] = g32[(size_t)k * half_np + t];

    vf4 a0 = {0,0,0,0}, a1 = a0, a2 = a0, a3 = a0;
    vf4 b0 = a0, b1 = a0, b2 = a0, b3 = a0;
    #pragma unroll
    for (int k = 0; k < 27; ++k) {
        const vf4* w = (const vf4*)&wlds[k * 16];   // uniform -> LDS broadcast
        vf4 w0 = w[0], w1 = w[1], w2 = w[2], w3 = w[3];
        float fa = __uint_as_float(gu[k] << 16);
        float fb = __uint_as_float(gu[k] & 0xFFFF0000u);
        a0 += fa * w0; a1 += fa * w1; a2 += fa * w2; a3 += fa * w3;
        b0 += fb * w0; b1 += fb * w1; b2 += fb * w2; b3 += fb * w3;
    }

    // streaming output, never re-read -> nontemporal, keep L2 for g
    vf4* op = (vf4*)(out + (size_t)o0 * 16);
    __builtin_nontemporal_store(a0, op + 0);
    __builtin_nontemporal_store(a1, op + 1);
    __builtin_nontemporal_store(a2, op + 2);
    __builtin_nontemporal_store(a3, op + 3);
    if (o0 + 1 < n_out) {
        __builtin_nontemporal_store(b0, op + 4);
        __builtin_nontemporal_store(b1, op + 5);
        __builtin_nontemporal_store(b2, op + 6);
        __builtin_nontemporal_store(b3, op + 7);
    }
}

// ---- fallback path (ws too small): known-correct atomic scatter ----
__global__ void __launch_bounds__(256)
sparse_conv_scatter_atomic(const float* __restrict__ feats,
                           const float* __restrict__ weight,
                           const int* __restrict__ in_idx,
                           const int* __restrict__ out_idx,
                           const int* __restrict__ k_idx,
                           float* __restrict__ out,
                           int M) {
    long long t = (long long)blockIdx.x * blockDim.x + threadIdx.x;
    int m = (int)(t >> 4);
    int c = (int)(t & 15);
    if (m >= M) return;
    float f = feats[in_idx[m]];
    float w = weight[k_idx[m] * 16 + c];
    atomicAdd(out + (long long)out_idx[m] * 16 + c, f * w);
}

extern "C" void kernel_launch(void* const* d_in, const int* in_sizes, int n_in,
                              void* d_out, int out_size, void* d_ws, size_t ws_size,
                              hipStream_t stream) {
    const float* feats  = (const float*)d_in[0];
    const float* weight = (const float*)d_in[1];
    const int*   in_idx = (const int*)d_in[2];
    const int*   out_idx= (const int*)d_in[3];
    const int*   k_idx  = (const int*)d_in[4];
    float*       out    = (float*)d_out;

    const int M     = in_sizes[2];        // rulebook length
    const int n_out = out_size / 16;      // out_size in FLOATS; rows of 16 f32
    const int np    = (n_out + 1) & ~1;   // even stride for u32-pair reads

    const size_t need = (size_t)27 * (size_t)np * sizeof(unsigned short); // ~105 MB
    const int block = 256;

    if (d_ws != nullptr && ws_size >= need) {
        unsigned short* g = (unsigned short*)d_ws;
        hipMemsetAsync(g, 0, need, stream);   // bf16 +0 == 0x0000

        const int nthr1 = (M + 3) / 4;
        const int grid1 = (nthr1 + block - 1) / block;
        scatter27<<<grid1, block, 0, stream>>>(feats, in_idx, out_idx,
                                               k_idx, g, M, np);

        const int nthr2 = (n_out + 1) / 2;
        const int grid2 = (nthr2 + block - 1) / block;
        reduce27<<<grid2, block, 0, stream>>>((const unsigned int*)g, weight,
                                              out, n_out, np / 2);
    } else {
        // d_out poisoned before every timed launch — zero it (out_size floats).
        hipMemsetAsync(d_out, 0, (size_t)out_size * sizeof(float), stream);
        const long long total = (long long)M * 16;
        const long long grid = (total + block - 1) / block;
        sparse_conv_scatter_atomic<<<(int)grid, block, 0, stream>>>(
            feats, weight, in_idx, out_idx, k_idx, out, M);
    }
}

// Round 12
// 254.606 us; speedup vs baseline: 3.7236x; 3.7236x over previous
//
#include <hip/hip_runtime.h>

// Sparse 3D conv (Cin=1, Cout=16), stride-2 — 27-plane two-pass.
//   pass 1: every entry: ONE bf16 store g[k][o] (no branches/atomics;
//           (o,k) unique by construction). 4 entries/thread for MLP.
//   pass 2: out[o,:] = sum_k g[k][o]*W[k,:]; 2 outputs/thread; weights
//           via compile-time k -> wave-uniform s_load (NO LDS tile).
//
// Round-11 lesson (hard-won): the LDS weight tile + full unroll inflated
// live ranges under the (256,4) 128-VGPR cap -> compiler spilled gu/acc
// to scratch (VGPR_Count=64, WRITE 1.66GB, 775us). R5's s_load variant
// fits (<=128) with zero VGPR cost for weights. Nontemporal stores were
// also reverted (bundled untested change).
// Round-6..10 lessons: no global counters, no sparse-path atomics, no
// fusion barriers — the branch-free 27-plane structure wins.

typedef float vf4 __attribute__((ext_vector_type(4)));
typedef int   vi4 __attribute__((ext_vector_type(4)));

__device__ inline unsigned short f32_to_bf16_rne(float x) {
    unsigned int u = __float_as_uint(x);
    unsigned int r = 0x7FFFu + ((u >> 16) & 1u);
    return (unsigned short)((u + r) >> 16);
}

__global__ void __launch_bounds__(256)
scatter27(const float* __restrict__ feats,
          const int* __restrict__ in_idx,
          const int* __restrict__ out_idx,
          const int* __restrict__ k_idx,
          unsigned short* __restrict__ g,
          int M, int np) {
    int t = blockIdx.x * blockDim.x + threadIdx.x;
    int base = t * 4;
    if (base + 3 < M) {
        vi4 kk = *(const vi4*)&k_idx[base];    // 16B coalesced
        vi4 ii = *(const vi4*)&in_idx[base];
        vi4 oo = *(const vi4*)&out_idx[base];
        // 4 independent gathers in flight (MLP)
        float f0 = feats[ii.x], f1 = feats[ii.y],
              f2 = feats[ii.z], f3 = feats[ii.w];
        // one unconditional 2B store per entry; k IS the plane index
        g[(size_t)kk.x * np + oo.x] = f32_to_bf16_rne(f0);
        g[(size_t)kk.y * np + oo.y] = f32_to_bf16_rne(f1);
        g[(size_t)kk.z * np + oo.z] = f32_to_bf16_rne(f2);
        g[(size_t)kk.w * np + oo.w] = f32_to_bf16_rne(f3);
    } else if (base < M) {
        for (int m = base; m < M; ++m)
            g[(size_t)k_idx[m] * np + out_idx[m]] =
                f32_to_bf16_rne(feats[in_idx[m]]);
    }
}

__global__ void __launch_bounds__(256, 4)
reduce27(const unsigned int* __restrict__ g32,  // 27 planes as u32 (2x bf16)
         const float* __restrict__ weight,      // [27][16] f32
         float* __restrict__ out,
         int n_out, int half_np) {
    int t = blockIdx.x * blockDim.x + threadIdx.x;
    int o0 = t * 2;
    if (o0 >= n_out) return;

    // 27 independent coalesced streams, kept packed (27 VGPRs)
    unsigned int gu[27];
    #pragma unroll
    for (int k = 0; k < 27; ++k)
        gu[k] = g32[(size_t)k * half_np + t];

    vf4 a0 = {0,0,0,0}, a1 = a0, a2 = a0, a3 = a0;
    vf4 b0 = a0, b1 = a0, b2 = a0, b3 = a0;
    #pragma unroll
    for (int k = 0; k < 27; ++k) {
        // compile-time k -> wave-uniform address -> s_load into SGPRs
        // (zero VGPR cost for weights; the R5-proven structure)
        const vf4* w = (const vf4*)&weight[k * 16];
        vf4 w0 = w[0], w1 = w[1], w2 = w[2], w3 = w[3];
        float fa = __uint_as_float(gu[k] << 16);
        float fb = __uint_as_float(gu[k] & 0xFFFF0000u);
        a0 += fa * w0; a1 += fa * w1; a2 += fa * w2; a3 += fa * w3;
        b0 += fb * w0; b1 += fb * w1; b2 += fb * w2; b3 += fb * w3;
    }

    vf4* op = (vf4*)(out + (size_t)o0 * 16);
    op[0] = a0; op[1] = a1; op[2] = a2; op[3] = a3;   // coalesced 64B
    if (o0 + 1 < n_out) {
        op[4] = b0; op[5] = b1; op[6] = b2; op[7] = b3;
    }
}

// ---- fallback path (ws too small): known-correct atomic scatter ----
__global__ void __launch_bounds__(256)
sparse_conv_scatter_atomic(const float* __restrict__ feats,
                           const float* __restrict__ weight,
                           const int* __restrict__ in_idx,
                           const int* __restrict__ out_idx,
                           const int* __restrict__ k_idx,
                           float* __restrict__ out,
                           int M) {
    long long t = (long long)blockIdx.x * blockDim.x + threadIdx.x;
    int m = (int)(t >> 4);
    int c = (int)(t & 15);
    if (m >= M) return;
    float f = feats[in_idx[m]];
    float w = weight[k_idx[m] * 16 + c];
    atomicAdd(out + (long long)out_idx[m] * 16 + c, f * w);
}

extern "C" void kernel_launch(void* const* d_in, const int* in_sizes, int n_in,
                              void* d_out, int out_size, void* d_ws, size_t ws_size,
                              hipStream_t stream) {
    const float* feats  = (const float*)d_in[0];
    const float* weight = (const float*)d_in[1];
    const int*   in_idx = (const int*)d_in[2];
    const int*   out_idx= (const int*)d_in[3];
    const int*   k_idx  = (const int*)d_in[4];
    float*       out    = (float*)d_out;

    const int M     = in_sizes[2];        // rulebook length
    const int n_out = out_size / 16;      // out_size in FLOATS; rows of 16 f32
    const int np    = (n_out + 1) & ~1;   // even stride for u32-pair reads

    const size_t need = (size_t)27 * (size_t)np * sizeof(unsigned short); // ~105 MB
    const int block = 256;

    if (d_ws != nullptr && ws_size >= need) {
        unsigned short* g = (unsigned short*)d_ws;
        hipMemsetAsync(g, 0, need, stream);   // bf16 +0 == 0x0000

        const int nthr1 = (M + 3) / 4;
        const int grid1 = (nthr1 + block - 1) / block;
        scatter27<<<grid1, block, 0, stream>>>(feats, in_idx, out_idx,
                                               k_idx, g, M, np);

        const int nthr2 = (n_out + 1) / 2;
        const int grid2 = (nthr2 + block - 1) / block;
        reduce27<<<grid2, block, 0, stream>>>((const unsigned int*)g, weight,
                                              out, n_out, np / 2);
    } else {
        // d_out poisoned before every timed launch — zero it (out_size floats).
        hipMemsetAsync(d_out, 0, (size_t)out_size * sizeof(float), stream);
        const long long total = (long long)M * 16;
        const long long grid = (total + block - 1) / block;
        sparse_conv_scatter_atomic<<<(int)grid, block, 0, stream>>>(
            feats, weight, in_idx, out_idx, k_idx, out, M);
    }
}